// Round 1
// baseline (978.313 us; speedup 1.0000x reference)
//
#include <hip/hip_runtime.h>

#define BATCH   8192
#define TSTEPS  256
#define FIN     64
#define HID     50
#define ROWS    16    // batch rows per wave (one wave per block, fully independent)
#define RSTRIDE 72    // f16 elements per LDS row (64 + 8 pad -> <=2-way banks, 16B aligned)

typedef _Float16 half8 __attribute__((ext_vector_type(8)));
typedef float    f32x4 __attribute__((ext_vector_type(4)));

__device__ __forceinline__ float tanh_fast(float v) {
    // tanh(x) = 1 - 2/(exp2(2*log2e*x)+1); exact at +-inf, ~1ulp hw exp/rcp
    float e = __builtin_amdgcn_exp2f(v * 2.8853900817779268f);
    return 1.0f - 2.0f * __builtin_amdgcn_rcpf(e + 1.0f);
}

__global__ __launch_bounds__(64, 1)
void rnn_fused(const float* __restrict__ x,
               const float* __restrict__ w_ih1, const float* __restrict__ w_hh1,
               const float* __restrict__ b_ih1, const float* __restrict__ b_hh1,
               const float* __restrict__ w_ih2, const float* __restrict__ w_hh2,
               const float* __restrict__ b_ih2, const float* __restrict__ b_hh2,
               const float* __restrict__ fc_w,  const float* __restrict__ fc_b,
               float* __restrict__ out)
{
    __shared__ __align__(16) _Float16 lds_h1[ROWS * RSTRIDE];
    __shared__ __align__(16) _Float16 lds_h2[ROWS * RSTRIDE];

    const int lane = threadIdx.x & 63;
    const int col  = lane & 15;   // MFMA m/n fast index
    const int quad = lane >> 4;   // MFMA k-chunk / row-group index
    const int rowbase = blockIdx.x * ROWS;

    // zero wave-private h state in LDS (t=0 reads zeros implicitly via regs anyway)
    for (int i = lane; i < ROWS * RSTRIDE; i += 64) {
        lds_h1[i] = (_Float16)0.0f;
        lds_h2[i] = (_Float16)0.0f;
    }
    __syncthreads();

    // ---- register-resident weight B-fragments, held for all 256 steps ----
    // B-operand layout: lane holds B[k][n] with n = col, k = kc*32 + quad*8 + i.
    // We need B[k][j] = W[j][k]  =>  element = W[jc*16+col][kc*32+quad*8+i].
    half8 Wih1f[2][4], Whh1f[2][4], Wih2f[2][4], Whh2f[2][4];
#pragma unroll
    for (int kc = 0; kc < 2; ++kc)
#pragma unroll
    for (int jc = 0; jc < 4; ++jc) {
        const int j = jc*16 + col;
        half8 a, b, c, d;
#pragma unroll
        for (int i = 0; i < 8; ++i) {
            const int k = kc*32 + quad*8 + i;
            a[i] = (_Float16)((j < HID)            ? w_ih1[j*FIN + k] : 0.0f); // [50][64]
            b[i] = (_Float16)((j < HID && k < HID) ? w_hh1[j*HID + k] : 0.0f); // [50][50]
            c[i] = (_Float16)((j < HID && k < HID) ? w_ih2[j*HID + k] : 0.0f);
            d[i] = (_Float16)((j < HID && k < HID) ? w_hh2[j*HID + k] : 0.0f);
        }
        Wih1f[kc][jc] = a; Whh1f[kc][jc] = b; Wih2f[kc][jc] = c; Whh2f[kc][jc] = d;
    }

    float bias1[4], bias2[4], fcwv[4];
#pragma unroll
    for (int jc = 0; jc < 4; ++jc) {
        const int j = jc*16 + col;
        bias1[jc] = (j < HID) ? b_ih1[j] + b_hh1[j] : 0.0f;  // ref adds both biases
        bias2[jc] = (j < HID) ? b_ih2[j] + b_hh2[j] : 0.0f;
        fcwv[jc]  = (j < HID) ? fc_w[j] : 0.0f;
    }

    // x A-fragment source: lane reads x[rowbase+col][t][quad*8 + i (+kc*32)]
    const float* xrow = x + (size_t)(rowbase + col) * TSTEPS * FIN + quad*8;

    half8 h1a[2] = {}, h2a[2] = {};  // A-frags of h1/h2 (zeros at t=0)
    f32x4 h2f[4];

    for (int t = 0; t < TSTEPS; ++t) {
        // x fragments: 2x (two aligned float4 loads + cvt to fp16)
        half8 xa[2];
#pragma unroll
        for (int kc = 0; kc < 2; ++kc) {
            f32x4 p0 = *(const f32x4*)(xrow + t*FIN + kc*32);
            f32x4 p1 = *(const f32x4*)(xrow + t*FIN + kc*32 + 4);
            half8 v;
#pragma unroll
            for (int i = 0; i < 4; ++i) { v[i] = (_Float16)p0[i]; v[i+4] = (_Float16)p1[i]; }
            xa[kc] = v;
        }

        // ---- layer 1: a1 = bias1 + x.Wih1^T + h1.Whh1^T ; h1 = tanh(a1) ----
        f32x4 h1f[4];
#pragma unroll
        for (int jc = 0; jc < 4; ++jc) {
            f32x4 acc = { bias1[jc], bias1[jc], bias1[jc], bias1[jc] };
            acc = __builtin_amdgcn_mfma_f32_16x16x32_f16(xa[0],  Wih1f[0][jc], acc, 0, 0, 0);
            acc = __builtin_amdgcn_mfma_f32_16x16x32_f16(xa[1],  Wih1f[1][jc], acc, 0, 0, 0);
            acc = __builtin_amdgcn_mfma_f32_16x16x32_f16(h1a[0], Whh1f[0][jc], acc, 0, 0, 0);
            acc = __builtin_amdgcn_mfma_f32_16x16x32_f16(h1a[1], Whh1f[1][jc], acc, 0, 0, 0);
#pragma unroll
            for (int r = 0; r < 4; ++r) acc[r] = tanh_fast(acc[r]);
            h1f[jc] = acc;
        }
        // C-layout -> A-layout via wave-private LDS (no barrier: single wave, in-order DS)
#pragma unroll
        for (int jc = 0; jc < 4; ++jc)
#pragma unroll
        for (int r = 0; r < 4; ++r)
            lds_h1[(quad*4 + r)*RSTRIDE + jc*16 + col] = (_Float16)h1f[jc][r];
#pragma unroll
        for (int kc = 0; kc < 2; ++kc)
            h1a[kc] = *(const half8*)&lds_h1[col*RSTRIDE + kc*32 + quad*8];

        // ---- layer 2: a2 = bias2 + h1.Wih2^T + h2.Whh2^T ; h2 = tanh(a2) ----
        // (h2a-dependent MFMAs first so the h1a LDS read latency overlaps)
#pragma unroll
        for (int jc = 0; jc < 4; ++jc) {
            f32x4 acc = { bias2[jc], bias2[jc], bias2[jc], bias2[jc] };
            acc = __builtin_amdgcn_mfma_f32_16x16x32_f16(h2a[0], Whh2f[0][jc], acc, 0, 0, 0);
            acc = __builtin_amdgcn_mfma_f32_16x16x32_f16(h2a[1], Whh2f[1][jc], acc, 0, 0, 0);
            acc = __builtin_amdgcn_mfma_f32_16x16x32_f16(h1a[0], Wih2f[0][jc], acc, 0, 0, 0);
            acc = __builtin_amdgcn_mfma_f32_16x16x32_f16(h1a[1], Wih2f[1][jc], acc, 0, 0, 0);
#pragma unroll
            for (int r = 0; r < 4; ++r) acc[r] = tanh_fast(acc[r]);
            h2f[jc] = acc;
        }
#pragma unroll
        for (int jc = 0; jc < 4; ++jc)
#pragma unroll
        for (int r = 0; r < 4; ++r)
            lds_h2[(quad*4 + r)*RSTRIDE + jc*16 + col] = (_Float16)h2f[jc][r];
#pragma unroll
        for (int kc = 0; kc < 2; ++kc)
            h2a[kc] = *(const half8*)&lds_h2[col*RSTRIDE + kc*32 + quad*8];
    }

    // ---- epilogue: out[row] = sigmoid(sum_j fc_w[j]*relu(h2_last[row][j]) + fc_b) ----
    // h2f C-layout: lane holds rows quad*4+r, col jc*16+col. Reduce over the 16 cols.
    float s[4];
#pragma unroll
    for (int r = 0; r < 4; ++r) {
        float v = 0.0f;
#pragma unroll
        for (int jc = 0; jc < 4; ++jc) {
            float h = h2f[jc][r];
            v += fcwv[jc] * (h > 0.0f ? h : 0.0f);
        }
        v += __shfl_xor(v, 1, 64);
        v += __shfl_xor(v, 2, 64);
        v += __shfl_xor(v, 4, 64);
        v += __shfl_xor(v, 8, 64);
        s[r] = v;
    }
    if (col == 0) {
        const float fb = fc_b[0];
#pragma unroll
        for (int r = 0; r < 4; ++r) {
            float z = s[r] + fb;
            float e = __builtin_amdgcn_exp2f(-z * 1.4426950408889634f);
            out[rowbase + quad*4 + r] = __builtin_amdgcn_rcpf(1.0f + e);
        }
    }
}

extern "C" void kernel_launch(void* const* d_in, const int* in_sizes, int n_in,
                              void* d_out, int out_size, void* d_ws, size_t ws_size,
                              hipStream_t stream) {
    (void)in_sizes; (void)n_in; (void)out_size; (void)d_ws; (void)ws_size;
    const float* x     = (const float*)d_in[0];
    const float* w_ih1 = (const float*)d_in[1];
    const float* w_hh1 = (const float*)d_in[2];
    const float* b_ih1 = (const float*)d_in[3];
    const float* b_hh1 = (const float*)d_in[4];
    const float* w_ih2 = (const float*)d_in[5];
    const float* w_hh2 = (const float*)d_in[6];
    const float* b_ih2 = (const float*)d_in[7];
    const float* b_hh2 = (const float*)d_in[8];
    const float* fc_w  = (const float*)d_in[9];
    const float* fc_b  = (const float*)d_in[10];
    float* out = (float*)d_out;

    rnn_fused<<<dim3(BATCH / ROWS), dim3(64), 0, stream>>>(
        x, w_ih1, w_hh1, b_ih1, b_hh1, w_ih2, w_hh2, b_ih2, b_hh2, fc_w, fc_b, out);
}

// Round 2
// 846.838 us; speedup vs baseline: 1.1553x; 1.1553x over previous
//
#include <hip/hip_runtime.h>

#define BATCH   8192
#define TSTEPS  256
#define FIN     64
#define HID     50
#define ROWS    16    // batch rows per block (one 16-row MFMA tile shared by 4 waves)
#define RSTRIDE 72    // f16 elements per LDS row (64 + 8 pad; 16B aligned, bank-staggered)
#define WPB     4     // waves per block; wave w owns output tile j in [w*16, w*16+16)

typedef _Float16 f16x8 __attribute__((ext_vector_type(8)));
typedef _Float16 f16x4 __attribute__((ext_vector_type(4)));
typedef float    f32x4 __attribute__((ext_vector_type(4)));

// Raw barrier: drain LDS only, leave global loads (x prefetch) in flight.
// __syncthreads() would emit s_waitcnt vmcnt(0) and kill the prefetch window.
#define BAR() asm volatile("s_waitcnt lgkmcnt(0)\n\ts_barrier" ::: "memory")

__device__ __forceinline__ float tanh_fast(float v) {
    // tanh(x) = 1 - 2/(exp2(2*log2e*x)+1); exact at +-inf
    float e = __builtin_amdgcn_exp2f(v * 2.8853900817779268f);
    return 1.0f - 2.0f * __builtin_amdgcn_rcpf(e + 1.0f);
}

__global__ __launch_bounds__(256, 2)
void rnn_fused(const float* __restrict__ x,
               const float* __restrict__ w_ih1, const float* __restrict__ w_hh1,
               const float* __restrict__ b_ih1, const float* __restrict__ b_hh1,
               const float* __restrict__ w_ih2, const float* __restrict__ w_hh2,
               const float* __restrict__ b_ih2, const float* __restrict__ b_hh2,
               const float* __restrict__ fc_w,  const float* __restrict__ fc_b,
               float* __restrict__ out)
{
    __shared__ __align__(16) _Float16 lds_x [2][ROWS * RSTRIDE];
    __shared__ __align__(16) _Float16 lds_h1[2][ROWS * RSTRIDE];
    __shared__ __align__(16) _Float16 lds_h2[2][ROWS * RSTRIDE];
    __shared__ float lds_red[WPB][ROWS];

    const int tid  = threadIdx.x;
    const int lane = tid & 63;
    const int wid  = tid >> 6;    // this wave's jc tile
    const int col  = lane & 15;   // MFMA m/n fast index
    const int quad = lane >> 4;   // MFMA k-chunk / row-group index
    const int rowbase = blockIdx.x * ROWS;

    // ---- this wave's weight B-fragments (jc = wid), register-resident ----
    // B-layout: lane holds B[k][n], n=col, k=kc*32+quad*8+i; B[k][j]=W[j][k].
    const int j = wid * 16 + col;
    f16x8 Wih1f[2], Whh1f[2], Wih2f[2], Whh2f[2];
#pragma unroll
    for (int kc = 0; kc < 2; ++kc) {
        f16x8 a, b, c, d;
#pragma unroll
        for (int i = 0; i < 8; ++i) {
            const int k = kc * 32 + quad * 8 + i;
            a[i] = (_Float16)((j < HID)            ? w_ih1[j * FIN + k] : 0.0f);
            b[i] = (_Float16)((j < HID && k < HID) ? w_hh1[j * HID + k] : 0.0f);
            c[i] = (_Float16)((j < HID && k < HID) ? w_ih2[j * HID + k] : 0.0f);
            d[i] = (_Float16)((j < HID && k < HID) ? w_hh2[j * HID + k] : 0.0f);
        }
        Wih1f[kc] = a; Whh1f[kc] = b; Wih2f[kc] = c; Whh2f[kc] = d;
    }
    const float bias1 = (j < HID) ? b_ih1[j] + b_hh1[j] : 0.0f;
    const float bias2 = (j < HID) ? b_ih2[j] + b_hh2[j] : 0.0f;
    const float fcw   = (j < HID) ? fc_w[j] : 0.0f;
    const float fcb   = fc_b[0];

    // ---- zero both h double-buffers (t=0 reads h(-1)=0 from LDS) ----
    for (int i = tid; i < 2 * ROWS * RSTRIDE; i += 256) {
        ((_Float16*)lds_h1)[i] = (_Float16)0.0f;
        ((_Float16*)lds_h2)[i] = (_Float16)0.0f;
    }

    // ---- cooperative x staging: wave w loads rows [w*4, w*4+4), 4 floats/lane ----
    const int xrow = wid * 4 + quad;
    const int xk   = col * 4;
    const float* xsrc = x + (size_t)(rowbase + xrow) * TSTEPS * FIN + xk;

    {   // prologue: stage x(0)
        f32x4 p = *(const f32x4*)xsrc;
        f16x4 v;
#pragma unroll
        for (int i = 0; i < 4; ++i) v[i] = (_Float16)p[i];
        *(f16x4*)&lds_x[0][xrow * RSTRIDE + xk] = v;
    }
    BAR();

    f16x8 h1a[2] = {};   // h1(t-1) A-frags, carried in regs (zeros at t=0)
    f32x4 h2f = {};      // this wave's h2 C-frag (final step survives for epilogue)

    for (int t = 0; t < TSTEPS; ++t) {
        const int cur = t & 1, nxt = cur ^ 1;

        // step-start LDS reads: x(t) and h2(t-1) A-frags
        f16x8 xa[2], h2a[2];
#pragma unroll
        for (int kc = 0; kc < 2; ++kc) {
            xa[kc]  = *(const f16x8*)&lds_x [cur][col * RSTRIDE + kc * 32 + quad * 8];
            h2a[kc] = *(const f16x8*)&lds_h2[nxt][col * RSTRIDE + kc * 32 + quad * 8];
        }

        // issue x(t+1) global prefetch; consumed at end of step (full-step window)
        const int tp = (t < TSTEPS - 1) ? t + 1 : TSTEPS - 1;
        const f32x4 xnext = *(const f32x4*)(xsrc + (size_t)tp * FIN);

        // ---- layer 1 (this wave's 16 j's): h1 = tanh(b1 + x.Wih1^T + h1.Whh1^T)
        f32x4 a1 = { bias1, bias1, bias1, bias1 };
        a1 = __builtin_amdgcn_mfma_f32_16x16x32_f16(xa[0],  Wih1f[0], a1, 0, 0, 0);
        a1 = __builtin_amdgcn_mfma_f32_16x16x32_f16(xa[1],  Wih1f[1], a1, 0, 0, 0);
        a1 = __builtin_amdgcn_mfma_f32_16x16x32_f16(h1a[0], Whh1f[0], a1, 0, 0, 0);
        a1 = __builtin_amdgcn_mfma_f32_16x16x32_f16(h1a[1], Whh1f[1], a1, 0, 0, 0);
#pragma unroll
        for (int r = 0; r < 4; ++r) a1[r] = tanh_fast(a1[r]);
        // publish C-frag (rows quad*4+r, col j) into h1 buffer
#pragma unroll
        for (int r = 0; r < 4; ++r)
            lds_h1[cur][(quad * 4 + r) * RSTRIDE + j] = (_Float16)a1[r];
        BAR();  // h1(t) visible; h2(t-1) reads already done

        // full h1(t) A-frags (used for layer2 now AND layer1 of t+1)
#pragma unroll
        for (int kc = 0; kc < 2; ++kc)
            h1a[kc] = *(const f16x8*)&lds_h1[cur][col * RSTRIDE + kc * 32 + quad * 8];

        // ---- layer 2: h2 = tanh(b2 + h1.Wih2^T + h2.Whh2^T)
        f32x4 a2 = { bias2, bias2, bias2, bias2 };
        a2 = __builtin_amdgcn_mfma_f32_16x16x32_f16(h2a[0], Whh2f[0], a2, 0, 0, 0);
        a2 = __builtin_amdgcn_mfma_f32_16x16x32_f16(h2a[1], Whh2f[1], a2, 0, 0, 0);
        a2 = __builtin_amdgcn_mfma_f32_16x16x32_f16(h1a[0], Wih2f[0], a2, 0, 0, 0);
        a2 = __builtin_amdgcn_mfma_f32_16x16x32_f16(h1a[1], Wih2f[1], a2, 0, 0, 0);
#pragma unroll
        for (int r = 0; r < 4; ++r) a2[r] = tanh_fast(a2[r]);
        h2f = a2;
#pragma unroll
        for (int r = 0; r < 4; ++r)
            lds_h2[cur][(quad * 4 + r) * RSTRIDE + j] = (_Float16)a2[r];

        // stage x(t+1) into the other buffer (vmcnt wait lands here, not at barriers)
        {
            f16x4 v;
#pragma unroll
            for (int i = 0; i < 4; ++i) v[i] = (_Float16)xnext[i];
            *(f16x4*)&lds_x[nxt][xrow * RSTRIDE + xk] = v;
        }
        BAR();  // h2(t), x(t+1) visible; everyone done reading cur-parity bufs
    }

    // ---- epilogue: out[row] = sigmoid(sum_j fcw[j]*relu(h2[row][j]) + fcb) ----
    // h2f: lane holds rows quad*4+r at col j. Partial over this wave's 16 j's.
    float s[4];
#pragma unroll
    for (int r = 0; r < 4; ++r) {
        float h = h2f[r];
        float c = fcw * (h > 0.0f ? h : 0.0f);
        c += __shfl_xor(c, 1, 64);
        c += __shfl_xor(c, 2, 64);
        c += __shfl_xor(c, 4, 64);
        c += __shfl_xor(c, 8, 64);
        s[r] = c;
    }
    if (col == 0) {
#pragma unroll
        for (int r = 0; r < 4; ++r) lds_red[wid][quad * 4 + r] = s[r];
    }
    BAR();
    if (wid == 0 && lane < ROWS) {
        float z = lds_red[0][lane] + lds_red[1][lane] + lds_red[2][lane]
                + lds_red[3][lane] + fcb;
        float e = __builtin_amdgcn_exp2f(-z * 1.4426950408889634f);
        out[rowbase + lane] = __builtin_amdgcn_rcpf(1.0f + e);
    }
}

extern "C" void kernel_launch(void* const* d_in, const int* in_sizes, int n_in,
                              void* d_out, int out_size, void* d_ws, size_t ws_size,
                              hipStream_t stream) {
    (void)in_sizes; (void)n_in; (void)out_size; (void)d_ws; (void)ws_size;
    const float* x     = (const float*)d_in[0];
    const float* w_ih1 = (const float*)d_in[1];
    const float* w_hh1 = (const float*)d_in[2];
    const float* b_ih1 = (const float*)d_in[3];
    const float* b_hh1 = (const float*)d_in[4];
    const float* w_ih2 = (const float*)d_in[5];
    const float* w_hh2 = (const float*)d_in[6];
    const float* b_ih2 = (const float*)d_in[7];
    const float* b_hh2 = (const float*)d_in[8];
    const float* fc_w  = (const float*)d_in[9];
    const float* fc_b  = (const float*)d_in[10];
    float* out = (float*)d_out;

    rnn_fused<<<dim3(BATCH / ROWS), dim3(WPB * 64), 0, stream>>>(
        x, w_ih1, w_hh1, b_ih1, b_hh1, w_ih2, w_hh2, b_ih2, b_hh2, fc_w, fc_b, out);
}